// Round 1
// baseline (5890.611 us; speedup 1.0000x reference)
//
#include <hip/hip_runtime.h>
#include <hip/hip_bf16.h>

// Problem constants
#define B_    128
#define T_    64
#define E_    300
#define HID_  1024
#define G4_   4096      // 4*HID
#define C_    512
#define NA_   196       // 14*14
#define KATT_ 512
#define MIMG_ 25088     // B_*NA_
#define MTOK_ 8192      // B_*T_

// ---------------------------------------------------------------------------
// 128x128 tile fp32 GEMM:  C[M,N] = A[M,K] @ Bw[N,K]^T (+bias +bias2)
// A rows optionally gathered via gidx (embedding). ldb == Kd.
// block 256 threads, 8x8 micro-tile, K-chunk 8.
// ---------------------------------------------------------------------------
__global__ __launch_bounds__(256) void gemm128(
    const float* __restrict__ A, int lda, const int* __restrict__ gidx,
    const float* __restrict__ Bw,
    const float* __restrict__ bias, const float* __restrict__ bias2,
    float* __restrict__ Cc, int ldc, int Kd)
{
  __shared__ float As[8][128];
  __shared__ float Bs[8][128];
  const int tid = threadIdx.x;
  const int m0 = blockIdx.y * 128, n0 = blockIdx.x * 128;
  const int lm = tid >> 1, lk = (tid & 1) * 4;
  long arow = m0 + lm;
  if (gidx) arow = (long)gidx[m0 + lm];
  const float* Ap = A + arow * (long)lda;
  const float* Bp = Bw + (long)(n0 + lm) * (long)Kd;
  const int ty = tid >> 4, tx = tid & 15;
  float acc[8][8];
#pragma unroll
  for (int i = 0; i < 8; i++)
#pragma unroll
    for (int j = 0; j < 8; j++) acc[i][j] = 0.f;

  for (int k0 = 0; k0 < Kd; k0 += 8) {
    if (k0 + 8 <= Kd) {
      float4 a4 = *(const float4*)(Ap + k0 + lk);
      float4 b4 = *(const float4*)(Bp + k0 + lk);
      As[lk+0][lm] = a4.x; As[lk+1][lm] = a4.y; As[lk+2][lm] = a4.z; As[lk+3][lm] = a4.w;
      Bs[lk+0][lm] = b4.x; Bs[lk+1][lm] = b4.y; Bs[lk+2][lm] = b4.z; Bs[lk+3][lm] = b4.w;
    } else {
#pragma unroll
      for (int q = 0; q < 4; q++) {
        int k = k0 + lk + q;
        As[lk+q][lm] = (k < Kd) ? Ap[k] : 0.f;
        Bs[lk+q][lm] = (k < Kd) ? Bp[k] : 0.f;
      }
    }
    __syncthreads();
#pragma unroll
    for (int kc = 0; kc < 8; kc++) {
      const float4 a0 = *(const float4*)&As[kc][ty*8];
      const float4 a1 = *(const float4*)&As[kc][ty*8+4];
      const float4 b0 = *(const float4*)&Bs[kc][tx*8];
      const float4 b1 = *(const float4*)&Bs[kc][tx*8+4];
      float ar[8] = {a0.x,a0.y,a0.z,a0.w,a1.x,a1.y,a1.z,a1.w};
      float br[8] = {b0.x,b0.y,b0.z,b0.w,b1.x,b1.y,b1.z,b1.w};
#pragma unroll
      for (int i = 0; i < 8; i++)
#pragma unroll
        for (int j = 0; j < 8; j++)
          acc[i][j] = fmaf(ar[i], br[j], acc[i][j]);
    }
    __syncthreads();
  }
#pragma unroll
  for (int i = 0; i < 8; i++) {
    long m = m0 + ty*8 + i;
    float* Cr = Cc + m * (long)ldc + (n0 + tx*8);
#pragma unroll
    for (int j = 0; j < 8; j++) {
      float v = acc[i][j];
      int n = n0 + tx*8 + j;
      if (bias)  v += bias[n];
      if (bias2) v += bias2[n];
      Cr[j] = v;
    }
  }
}

// ---------------------------------------------------------------------------
// 64x64 tile fp32 GEMM with split-K (blockIdx.z): partial z writes to
// Cc + z*Cstride. Used for the M=128 LSTM recurrent GEMM (split-K=2 to get
// 256 blocks on 256 CUs) and the tiny t_u GEMM.
// ---------------------------------------------------------------------------
__global__ __launch_bounds__(256) void gemm64(
    const float* __restrict__ A, int lda,
    const float* __restrict__ Bw,
    const float* __restrict__ bias,
    float* __restrict__ Cc, int ldc, long Cstride,
    int Kd, int kper)
{
  __shared__ float As[16][64];
  __shared__ float Bs[16][64];
  const int tid = threadIdx.x;
  const int m0 = blockIdx.y * 64, n0 = blockIdx.x * 64;
  const int kbeg = blockIdx.z * kper;
  const int kend = min(Kd, kbeg + kper);
  float* Cz = Cc + (long)blockIdx.z * Cstride;
  const int lm = tid >> 2, lk = (tid & 3) * 4;
  const float* Ap = A + (long)(m0 + lm) * (long)lda;
  const float* Bp = Bw + (long)(n0 + lm) * (long)Kd;
  const int ty = tid >> 4, tx = tid & 15;
  float acc[4][4];
#pragma unroll
  for (int i = 0; i < 4; i++)
#pragma unroll
    for (int j = 0; j < 4; j++) acc[i][j] = 0.f;

  for (int k0 = kbeg; k0 < kend; k0 += 16) {
#pragma unroll
    for (int q = 0; q < 4; q++) {
      int k = k0 + lk + q;
      bool ok = k < kend;
      As[lk+q][lm] = ok ? Ap[k] : 0.f;
      Bs[lk+q][lm] = ok ? Bp[k] : 0.f;
    }
    __syncthreads();
#pragma unroll
    for (int kc = 0; kc < 16; kc++) {
      const float4 a4 = *(const float4*)&As[kc][ty*4];
      const float4 b4 = *(const float4*)&Bs[kc][tx*4];
      float ar[4] = {a4.x, a4.y, a4.z, a4.w};
      float br[4] = {b4.x, b4.y, b4.z, b4.w};
#pragma unroll
      for (int i = 0; i < 4; i++)
#pragma unroll
        for (int j = 0; j < 4; j++)
          acc[i][j] = fmaf(ar[i], br[j], acc[i][j]);
    }
    __syncthreads();
  }
#pragma unroll
  for (int i = 0; i < 4; i++) {
    long m = m0 + ty*4 + i;
    float* Cr = Cz + m * (long)ldc + (n0 + tx*4);
#pragma unroll
    for (int j = 0; j < 4; j++) {
      float v = acc[i][j];
      if (bias) v += bias[n0 + tx*4 + j];
      Cr[j] = v;
    }
  }
}

// ---------------------------------------------------------------------------
// LSTM pointwise: g = Xg_t + gpart0 + gpart1 ; torch gate order i,f,g,o
// c' = sig(f)*c + sig(i)*tanh(g) ; h' = sig(o)*tanh(c')
// ---------------------------------------------------------------------------
__global__ __launch_bounds__(256) void lstm_gates(
    const float* __restrict__ Xg_t, const float* __restrict__ gp,
    float* __restrict__ cst, float* __restrict__ hout)
{
  int idx = blockIdx.x * 256 + threadIdx.x;   // 0..131071 = b*1024 + j
  int b = idx >> 10, j = idx & 1023;
  long base = (long)b * 4096 + j;
  float gi = Xg_t[base       ] + gp[base       ] + gp[524288 + base       ];
  float gf = Xg_t[base + 1024] + gp[base + 1024] + gp[524288 + base + 1024];
  float gg = Xg_t[base + 2048] + gp[base + 2048] + gp[524288 + base + 2048];
  float go = Xg_t[base + 3072] + gp[base + 3072] + gp[524288 + base + 3072];
  float si = 1.f / (1.f + expf(-gi));
  float sf = 1.f / (1.f + expf(-gf));
  float so = 1.f / (1.f + expf(-go));
  float cn = sf * cst[idx] + si * tanhf(gg);
  cst[idx] = cn;
  hout[idx] = so * tanhf(cn);
}

// ---------------------------------------------------------------------------
// score[row] = sum_k tanh(t_img[row,k] + t_u[b,k]) * wl_p[k]   (row = b*196+n)
// one block (256 thr) per row, K=512
// ---------------------------------------------------------------------------
__global__ __launch_bounds__(256) void attn_score(
    const float* __restrict__ t_img, const float* __restrict__ t_u,
    const float* __restrict__ wp, float* __restrict__ sc)
{
  int row = blockIdx.x;
  int b = row / NA_;
  int tid = threadIdx.x;
  const float* tr = t_img + (long)row * KATT_;
  const float* tu = t_u + (long)b * KATT_;
  float s = tanhf(tr[tid]       + tu[tid])       * wp[tid]
          + tanhf(tr[tid + 256] + tu[tid + 256]) * wp[tid + 256];
#pragma unroll
  for (int off = 32; off; off >>= 1) s += __shfl_down(s, off, 64);
  __shared__ float red[4];
  if ((tid & 63) == 0) red[tid >> 6] = s;
  __syncthreads();
  if (tid == 0) sc[row] = red[0] + red[1] + red[2] + red[3];
}

// ---------------------------------------------------------------------------
// per-b: p = softmax(sc[b,:196]); u[b,h] += sum_n out_img_flat[b,h*196+n]*p[n]
// (faithful reshape: temp[b][h][n] = out_img flat at b*200704 + h*196 + n)
// ---------------------------------------------------------------------------
__global__ __launch_bounds__(256) void softmax_pool(
    const float* __restrict__ sc, const float* __restrict__ outimg,
    float* __restrict__ u)
{
  int b = blockIdx.x, tid = threadIdx.x;
  __shared__ float p[NA_];
  __shared__ float red[8];
  float v = (tid < NA_) ? sc[b * NA_ + tid] : -1e30f;
  float m = v;
#pragma unroll
  for (int off = 32; off; off >>= 1) m = fmaxf(m, __shfl_down(m, off, 64));
  if ((tid & 63) == 0) red[tid >> 6] = m;
  __syncthreads();
  float bm = fmaxf(fmaxf(red[0], red[1]), fmaxf(red[2], red[3]));
  float e = (tid < NA_) ? expf(v - bm) : 0.f;
  float s = e;
#pragma unroll
  for (int off = 32; off; off >>= 1) s += __shfl_down(s, off, 64);
  if ((tid & 63) == 0) red[4 + (tid >> 6)] = s;
  __syncthreads();
  float bs = red[4] + red[5] + red[6] + red[7];
  if (tid < NA_) p[tid] = e / bs;
  __syncthreads();
  const float* base = outimg + (long)b * (HID_ * NA_);
  for (int h = tid; h < HID_; h += 256) {
    const float* r = base + h * NA_;
    float acc = 0.f;
#pragma unroll 4
    for (int n = 0; n < NA_; n++) acc = fmaf(r[n], p[n], acc);
    u[b * HID_ + h] += acc;
  }
}

// ---------------------------------------------------------------------------
// Workspace layout (floats). Peak ~192 MB.
//  [0, 33554432)            Xg [8192,4096]  -- reused as out_img [25088,1024] after LSTM
//  [33554432, 46399488)     t_img [25088,512]
//  then h0,h1,c (131072 ea), gbuf (2x524288 split-K partials), t_u (65536), sc (25088)
// ---------------------------------------------------------------------------
extern "C" void kernel_launch(void* const* d_in, const int* in_sizes, int n_in,
                              void* d_out, int out_size, void* d_ws, size_t ws_size,
                              hipStream_t stream) {
  const int*   desc   = (const int*)  d_in[0];
  const float* img    = (const float*)d_in[1];
  const float* emb    = (const float*)d_in[2];
  const float* W_ih   = (const float*)d_in[3];
  const float* W_hh   = (const float*)d_in[4];
  const float* b_ih   = (const float*)d_in[5];
  const float* b_hh   = (const float*)d_in[6];
  const float* W_img  = (const float*)d_in[7];
  const float* b_img  = (const float*)d_in[8];
  const float* Wl_img = (const float*)d_in[9];
  const float* Wl_q   = (const float*)d_in[10];
  const float* bl_q   = (const float*)d_in[11];
  const float* wl_p   = (const float*)d_in[12];
  // d_in[13] = bl_p: scalar shift inside softmax -> no-op, unused.
  float* u = (float*)d_out;

  float* W      = (float*)d_ws;
  float* Xg     = W;                       // 33,554,432 f
  float* outimg = W;                       // alias (Xg dead after LSTM)
  float* timg   = W + 33554432;            // 12,845,056 f
  float* h0     = W + 46399488;
  float* h1     = h0 + 131072;
  float* cbuf   = h1 + 131072;
  float* gbuf   = cbuf + 131072;           // 2 * 524288 (split-K partials)
  float* tu     = gbuf + 1048576;
  float* scb    = tu + 65536;

  hipMemsetAsync(h0, 0, 131072 * sizeof(float), stream);
  hipMemsetAsync(cbuf, 0, 131072 * sizeof(float), stream);

  // Xg = emb[desc] @ W_ih^T + b_ih + b_hh   (M=8192, N=4096, K=300)
  gemm128<<<dim3(32, 64), 256, 0, stream>>>(emb, E_, desc, W_ih, b_ih, b_hh,
                                            Xg, G4_, E_);

  // LSTM: 64 steps; recurrent GEMM (M=128,N=4096,K=1024) split-K=2 -> 256 blocks
  for (int t = 0; t < T_; t++) {
    float* hin  = (t & 1) ? h1 : h0;
    float* hout = (t & 1) ? h0 : h1;
    gemm64<<<dim3(64, 2, 2), 256, 0, stream>>>(hin, HID_, W_hh, nullptr,
                                               gbuf, G4_, 524288L, HID_, 512);
    lstm_gates<<<512, 256, 0, stream>>>(Xg + (long)t * B_ * G4_, gbuf, cbuf, hout);
  }
  // u_k = h_T  (after t=63, final h lives in h0)
  hipMemcpyAsync(u, h0, 131072 * sizeof(float), hipMemcpyDeviceToDevice, stream);

  // out_img = img_flat[25088,512] @ W_img^T + b_img   (M=25088, N=1024, K=512)
  gemm128<<<dim3(8, 196), 256, 0, stream>>>(img, C_, nullptr, W_img, b_img, nullptr,
                                            outimg, HID_, C_);

  for (int i = 0; i < 2; i++) {
    // t_u = u @ Wl_q[i]^T + bl_q[i]    (M=128, N=512, K=1024)
    gemm64<<<dim3(8, 2, 1), 256, 0, stream>>>(u, HID_, Wl_q + (long)i * KATT_ * HID_,
                                              bl_q + i * KATT_, tu, KATT_, 0L,
                                              HID_, HID_);
    // t_img = out_img @ Wl_img[i]^T    (M=25088, N=512, K=1024)
    gemm128<<<dim3(4, 196), 256, 0, stream>>>(outimg, HID_, nullptr,
                                              Wl_img + (long)i * KATT_ * HID_,
                                              nullptr, nullptr, timg, KATT_, HID_);
    // scores + softmax + pooling, u += v
    attn_score<<<MIMG_, 256, 0, stream>>>(timg, tu, wl_p + i * KATT_, scb);
    softmax_pool<<<B_, 256, 0, stream>>>(scb, outimg, u);
  }
}

// Round 2
// 2182.660 us; speedup vs baseline: 2.6988x; 2.6988x over previous
//
#include <hip/hip_runtime.h>
#include <hip/hip_bf16.h>

#define B_    128
#define T_    64
#define E_    300
#define HID_  1024
#define G4_   4096
#define C_    512
#define NA_   196
#define KATT_ 512
#define MIMG_ 25088

typedef short s16x8 __attribute__((ext_vector_type(8)));
typedef float f32x4 __attribute__((ext_vector_type(4)));

__device__ __forceinline__ unsigned short f2bf(float f) {
  __hip_bfloat16 h = __float2bfloat16(f);
  return __builtin_bit_cast(unsigned short, h);
}
__device__ __forceinline__ float bf2f(unsigned short u) {
  __hip_bfloat16 h = __builtin_bit_cast(__hip_bfloat16, u);
  return __bfloat162float(h);
}

// ---------------------------------------------------------------------------
// generic fp32 -> bf16 convert
// ---------------------------------------------------------------------------
__global__ __launch_bounds__(256) void conv_bf16(const float* __restrict__ in,
                                                 unsigned short* __restrict__ out,
                                                 int n) {
  int i = blockIdx.x * 256 + threadIdx.x;
  if (i < n) out[i] = f2bf(in[i]);
}

// pad K 300 -> 320 while converting: out[r][k] = k<300 ? bf16(in[r*300+k]) : 0
__global__ __launch_bounds__(256) void conv_pad320(const float* __restrict__ in,
                                                   unsigned short* __restrict__ out,
                                                   int rows) {
  int i = blockIdx.x * 256 + threadIdx.x;
  if (i >= rows * 320) return;
  int r = i / 320, k = i - r * 320;
  out[i] = (k < 300) ? f2bf(in[(size_t)r * 300 + k]) : (unsigned short)0;
}

// gathered embedding rows -> bf16 [8192 x 320] (row m = t*128+b => desc_flat[m])
__global__ __launch_bounds__(256) void gather_emb(const int* __restrict__ desc,
                                                  const float* __restrict__ emb,
                                                  unsigned short* __restrict__ out) {
  int i = blockIdx.x * 256 + threadIdx.x;   // 8192*320
  int m = i / 320, k = i - m * 320;
  float v = (k < 300) ? emb[(size_t)desc[m] * 300 + k] : 0.f;
  out[i] = f2bf(v);
}

// ---------------------------------------------------------------------------
// bf16 MFMA GEMM, 128x128 tile, BK=32, 4 waves each 64x64 (16 MFMA tiles).
// C[M,N] = A[M,K] @ Bw[N,K]^T (+bias +bias2). Output fp32 (Cf) or bf16 (Cb).
// LDS rows padded to 40 ushorts (80 B) to break ds_read_b128 bank conflicts.
// ---------------------------------------------------------------------------
__global__ __launch_bounds__(256) void gemm_mfma(
    const unsigned short* __restrict__ A, int lda,
    const unsigned short* __restrict__ Bw, int Kd,
    const float* __restrict__ bias, const float* __restrict__ bias2,
    float* __restrict__ Cf, unsigned short* __restrict__ Cb, int ldc)
{
  __shared__ unsigned short As[128 * 40];
  __shared__ unsigned short Bs[128 * 40];
  const int tid = threadIdx.x;
  const int m0 = blockIdx.y << 7, n0 = blockIdx.x << 7;
  const int w = tid >> 6, l = tid & 63;
  const int wr = w >> 1, wc = w & 1;
  const int lrow = l & 15, lk = (l >> 4) << 3;
  const int srow = tid >> 2, schunk = (tid & 3) << 3;

  f32x4 acc[4][4];
#pragma unroll
  for (int i = 0; i < 4; i++)
#pragma unroll
    for (int j = 0; j < 4; j++) acc[i][j] = (f32x4){0.f, 0.f, 0.f, 0.f};

  const unsigned short* Ap = A + (size_t)(m0 + srow) * lda + schunk;
  const unsigned short* Bp = Bw + (size_t)(n0 + srow) * Kd + schunk;
  const size_t arep = (size_t)64 * lda, brep = (size_t)64 * Kd;

  for (int k0 = 0; k0 < Kd; k0 += 32) {
    *(uint4*)&As[srow * 40 + schunk]        = *(const uint4*)(Ap + k0);
    *(uint4*)&As[(srow + 64) * 40 + schunk] = *(const uint4*)(Ap + arep + k0);
    *(uint4*)&Bs[srow * 40 + schunk]        = *(const uint4*)(Bp + k0);
    *(uint4*)&Bs[(srow + 64) * 40 + schunk] = *(const uint4*)(Bp + brep + k0);
    __syncthreads();
    s16x8 af[4], bfr[4];
#pragma unroll
    for (int i = 0; i < 4; i++) {
      af[i]  = *(const s16x8*)&As[(wr * 64 + i * 16 + lrow) * 40 + lk];
      bfr[i] = *(const s16x8*)&Bs[(wc * 64 + i * 16 + lrow) * 40 + lk];
    }
#pragma unroll
    for (int i = 0; i < 4; i++)
#pragma unroll
      for (int j = 0; j < 4; j++)
        acc[i][j] = __builtin_amdgcn_mfma_f32_16x16x32_bf16(af[i], bfr[j], acc[i][j], 0, 0, 0);
    __syncthreads();
  }

#pragma unroll
  for (int i = 0; i < 4; i++) {
    int rbase = m0 + wr * 64 + i * 16 + (l >> 4) * 4;
#pragma unroll
    for (int j = 0; j < 4; j++) {
      int col = n0 + wc * 64 + j * 16 + lrow;
      float badd = (bias ? bias[col] : 0.f) + (bias2 ? bias2[col] : 0.f);
#pragma unroll
      for (int r = 0; r < 4; r++) {
        float v = acc[i][j][r] + badd;
        size_t off = (size_t)(rbase + r) * ldc + col;
        if (Cf) Cf[off] = v;
        else    Cb[off] = f2bf(v);
      }
    }
  }
}

// ---------------------------------------------------------------------------
// Fused LSTM step. Grid 128: block -> (mh = batch half, jb = 16-wide j block).
// Wave w computes gate w: C[64x16] = h_in[64x1024] @ W_hh[w*1024+j0 .. +15]^T
// via 16x16x32 MFMA straight from L2. Then gates i,f,g,o combine through LDS.
// ---------------------------------------------------------------------------
__global__ __launch_bounds__(256) void lstm_step(
    const unsigned short* __restrict__ h_in,   // [128,1024] bf16
    const unsigned short* __restrict__ Xg,     // [128,4096] bf16 (rows of step t)
    const unsigned short* __restrict__ Whh,    // [4096,1024] bf16
    float* __restrict__ c,                     // [128,1024] fp32
    unsigned short* __restrict__ h_out,        // [128,1024] bf16
    float* __restrict__ u_final)               // null, or [128,1024] fp32
{
  const int tid = threadIdx.x;
  const int w = tid >> 6, l = tid & 63;
  const int mh = blockIdx.x & 1;
  const int j0 = (blockIdx.x >> 1) << 4;
  const int lrow = l & 15, lk = (l >> 4) << 3;

  f32x4 acc[4];
#pragma unroll
  for (int mi = 0; mi < 4; mi++) acc[mi] = (f32x4){0.f, 0.f, 0.f, 0.f};

  const unsigned short* Bp = Whh + ((size_t)(w * 1024 + j0 + lrow)) * 1024 + lk;
  const unsigned short* Ap = h_in + ((size_t)(mh * 64 + lrow)) * 1024 + lk;

#pragma unroll 4
  for (int kc = 0; kc < 32; kc++) {
    s16x8 b = *(const s16x8*)(Bp + kc * 32);
#pragma unroll
    for (int mi = 0; mi < 4; mi++) {
      s16x8 a = *(const s16x8*)(Ap + (size_t)mi * 16 * 1024 + kc * 32);
      acc[mi] = __builtin_amdgcn_mfma_f32_16x16x32_bf16(a, b, acc[mi], 0, 0, 0);
    }
  }

  __shared__ float Gs[4][64][17];
#pragma unroll
  for (int mi = 0; mi < 4; mi++)
#pragma unroll
    for (int r = 0; r < 4; r++)
      Gs[w][mi * 16 + (l >> 4) * 4 + r][lrow] = acc[mi][r];
  __syncthreads();

#pragma unroll
  for (int q = 0; q < 4; q++) {
    int e = tid + q * 256;          // 0..1023 = row*16+col
    int row = e >> 4, col = e & 15;
    int b_ = mh * 64 + row, j = j0 + col;
    size_t xbase = (size_t)b_ * 4096 + j;
    float gi = bf2f(Xg[xbase])        + Gs[0][row][col];
    float gf = bf2f(Xg[xbase + 1024]) + Gs[1][row][col];
    float gg = bf2f(Xg[xbase + 2048]) + Gs[2][row][col];
    float go = bf2f(Xg[xbase + 3072]) + Gs[3][row][col];
    float si = 1.f / (1.f + expf(-gi));
    float sf = 1.f / (1.f + expf(-gf));
    float so = 1.f / (1.f + expf(-go));
    size_t ci = (size_t)b_ * 1024 + j;
    float cn = sf * c[ci] + si * tanhf(gg);
    c[ci] = cn;
    float hn = so * tanhf(cn);
    h_out[ci] = f2bf(hn);
    if (u_final) u_final[ci] = hn;
  }
}

// ---------------------------------------------------------------------------
// fp32 64x64 GEMM (kept for tiny t_u: M=128,N=512,K=1024)
// ---------------------------------------------------------------------------
__global__ __launch_bounds__(256) void gemm64(
    const float* __restrict__ A, int lda,
    const float* __restrict__ Bw,
    const float* __restrict__ bias,
    float* __restrict__ Cc, int ldc, int Kd)
{
  __shared__ float As[16][64];
  __shared__ float Bs[16][64];
  const int tid = threadIdx.x;
  const int m0 = blockIdx.y * 64, n0 = blockIdx.x * 64;
  const int lm = tid >> 2, lk = (tid & 3) * 4;
  const float* Ap = A + (size_t)(m0 + lm) * lda;
  const float* Bp = Bw + (size_t)(n0 + lm) * Kd;
  const int ty = tid >> 4, tx = tid & 15;
  float acc[4][4];
#pragma unroll
  for (int i = 0; i < 4; i++)
#pragma unroll
    for (int j = 0; j < 4; j++) acc[i][j] = 0.f;

  for (int k0 = 0; k0 < Kd; k0 += 16) {
#pragma unroll
    for (int q = 0; q < 4; q++) {
      int k = k0 + lk + q;
      As[lk + q][lm] = Ap[k];
      Bs[lk + q][lm] = Bp[k];
    }
    __syncthreads();
#pragma unroll
    for (int kc = 0; kc < 16; kc++) {
      const float4 a4 = *(const float4*)&As[kc][ty * 4];
      const float4 b4 = *(const float4*)&Bs[kc][tx * 4];
      float ar[4] = {a4.x, a4.y, a4.z, a4.w};
      float br[4] = {b4.x, b4.y, b4.z, b4.w};
#pragma unroll
      for (int i = 0; i < 4; i++)
#pragma unroll
        for (int j = 0; j < 4; j++)
          acc[i][j] = fmaf(ar[i], br[j], acc[i][j]);
    }
    __syncthreads();
  }
#pragma unroll
  for (int i = 0; i < 4; i++) {
    float* Cr = Cc + (size_t)(m0 + ty * 4 + i) * ldc + (n0 + tx * 4);
#pragma unroll
    for (int j = 0; j < 4; j++) {
      float v = acc[i][j];
      if (bias) v += bias[n0 + tx * 4 + j];
      Cr[j] = v;
    }
  }
}

// ---------------------------------------------------------------------------
// score[row] = sum_k tanh(t_img[row,k] + t_u[b,k]) * wl_p[k]
// ---------------------------------------------------------------------------
__global__ __launch_bounds__(256) void attn_score(
    const float* __restrict__ t_img, const float* __restrict__ t_u,
    const float* __restrict__ wp, float* __restrict__ sc)
{
  int row = blockIdx.x;
  int b = row / NA_;
  int tid = threadIdx.x;
  const float* tr = t_img + (size_t)row * KATT_;
  const float* tu = t_u + (size_t)b * KATT_;
  float s = tanhf(tr[tid]       + tu[tid])       * wp[tid]
          + tanhf(tr[tid + 256] + tu[tid + 256]) * wp[tid + 256];
#pragma unroll
  for (int off = 32; off; off >>= 1) s += __shfl_down(s, off, 64);
  __shared__ float red[4];
  if ((tid & 63) == 0) red[tid >> 6] = s;
  __syncthreads();
  if (tid == 0) sc[row] = red[0] + red[1] + red[2] + red[3];
}

// ---------------------------------------------------------------------------
// per-b softmax over 196 + pooled v; u += v. outimg is bf16.
// temp[b][h][n] = outimg flat at b*200704 + h*196 + n (faithful reshape)
// ---------------------------------------------------------------------------
__global__ __launch_bounds__(256) void softmax_pool(
    const float* __restrict__ sc, const unsigned short* __restrict__ outimg,
    float* __restrict__ u)
{
  int b = blockIdx.x, tid = threadIdx.x;
  __shared__ float p[NA_];
  __shared__ float red[8];
  float v = (tid < NA_) ? sc[b * NA_ + tid] : -1e30f;
  float m = v;
#pragma unroll
  for (int off = 32; off; off >>= 1) m = fmaxf(m, __shfl_down(m, off, 64));
  if ((tid & 63) == 0) red[tid >> 6] = m;
  __syncthreads();
  float bm = fmaxf(fmaxf(red[0], red[1]), fmaxf(red[2], red[3]));
  float e = (tid < NA_) ? expf(v - bm) : 0.f;
  float s = e;
#pragma unroll
  for (int off = 32; off; off >>= 1) s += __shfl_down(s, off, 64);
  if ((tid & 63) == 0) red[4 + (tid >> 6)] = s;
  __syncthreads();
  float bs = red[4] + red[5] + red[6] + red[7];
  if (tid < NA_) p[tid] = e / bs;
  __syncthreads();
  const unsigned short* base = outimg + (size_t)b * (HID_ * NA_);
  for (int h = tid; h < HID_; h += 256) {
    const unsigned short* r = base + h * NA_;
    float acc = 0.f;
#pragma unroll 4
    for (int n = 0; n < NA_; n++) acc = fmaf(bf2f(r[n]), p[n], acc);
    u[b * HID_ + h] += acc;
  }
}

// ---------------------------------------------------------------------------
extern "C" void kernel_launch(void* const* d_in, const int* in_sizes, int n_in,
                              void* d_out, int out_size, void* d_ws, size_t ws_size,
                              hipStream_t stream) {
  const int*   desc   = (const int*)  d_in[0];
  const float* img    = (const float*)d_in[1];
  const float* emb    = (const float*)d_in[2];
  const float* W_ih   = (const float*)d_in[3];
  const float* W_hh   = (const float*)d_in[4];
  const float* b_ih   = (const float*)d_in[5];
  const float* b_hh   = (const float*)d_in[6];
  const float* W_img  = (const float*)d_in[7];
  const float* b_img  = (const float*)d_in[8];
  const float* Wl_img = (const float*)d_in[9];
  const float* Wl_q   = (const float*)d_in[10];
  const float* bl_q   = (const float*)d_in[11];
  const float* wl_p   = (const float*)d_in[12];
  float* u = (float*)d_out;

  // ---- workspace layout (bytes) ----
  uint8_t* base = (uint8_t*)d_ws;
  unsigned short* Xgb    = (unsigned short*)(base);              // 67,108,864 B
  float*          timg   = (float*)(base);                       // alias (Xg dead after LSTM)
  unsigned short* Aemb   = (unsigned short*)(base + 67108864);   //  5,242,880
  unsigned short* Wihb   = (unsigned short*)(base + 72351744);   //  2,621,440
  unsigned short* Whhb   = (unsigned short*)(base + 74973184);   //  8,388,608
  unsigned short* imgb   = (unsigned short*)(base + 83361792);   // 25,690,112
  unsigned short* Wimgb  = (unsigned short*)(base + 109051904);  //  1,048,576
  unsigned short* Wlimgb = (unsigned short*)(base + 110100480);  //  2,097,152
  unsigned short* outimg = (unsigned short*)(base + 112197632);  // 51,380,224
  unsigned short* h0     = (unsigned short*)(base + 163577856);  //    262,144
  unsigned short* h1     = (unsigned short*)(base + 163840000);  //    262,144
  float*          cbuf   = (float*)(base + 164102144);           //    524,288
  float*          tu     = (float*)(base + 164626432);           //    262,144
  float*          scb    = (float*)(base + 164888576);           //    100,352

  // ---- bf16 conversions / gathers ----
  conv_bf16<<<(G4_ * HID_ + 255) / 256, 256, 0, stream>>>(W_hh, Whhb, G4_ * HID_);
  conv_pad320<<<(G4_ * 320 + 255) / 256, 256, 0, stream>>>(W_ih, Wihb, G4_);
  gather_emb<<<(8192 * 320) / 256, 256, 0, stream>>>(desc, emb, Aemb);
  conv_bf16<<<(MIMG_ * C_ + 255) / 256, 256, 0, stream>>>(img, imgb, MIMG_ * C_);
  conv_bf16<<<(HID_ * C_ + 255) / 256, 256, 0, stream>>>(W_img, Wimgb, HID_ * C_);
  conv_bf16<<<(2 * KATT_ * HID_ + 255) / 256, 256, 0, stream>>>(Wl_img, Wlimgb, 2 * KATT_ * HID_);

  // Xg = emb[desc] @ W_ih^T + b_ih + b_hh  -> bf16 [8192,4096]
  gemm_mfma<<<dim3(32, 64), 256, 0, stream>>>(Aemb, 320, Wihb, 320, b_ih, b_hh,
                                              nullptr, Xgb, G4_);

  hipMemsetAsync(h0, 0, 262144, stream);
  hipMemsetAsync(cbuf, 0, 524288, stream);

  // ---- LSTM: 64 fused steps ----
  for (int t = 0; t < T_; t++) {
    unsigned short* hin  = (t & 1) ? h1 : h0;
    unsigned short* hout = (t & 1) ? h0 : h1;
    lstm_step<<<128, 256, 0, stream>>>(hin, Xgb + (size_t)t * B_ * G4_, Whhb,
                                       cbuf, hout, (t == T_ - 1) ? u : nullptr);
  }

  // out_img = img @ W_img^T + b_img -> bf16 [25088,1024]
  gemm_mfma<<<dim3(8, 196), 256, 0, stream>>>(imgb, C_, Wimgb, C_, b_img, nullptr,
                                              nullptr, outimg, HID_);

  for (int i = 0; i < 2; i++) {
    // t_u = u @ Wl_q[i]^T + bl_q[i]  (fp32, tiny)
    gemm64<<<dim3(8, 2), 256, 0, stream>>>(u, HID_, Wl_q + (size_t)i * KATT_ * HID_,
                                           bl_q + i * KATT_, tu, KATT_, HID_);
    // t_img = out_img @ Wl_img[i]^T  -> fp32 [25088,512]
    gemm_mfma<<<dim3(4, 196), 256, 0, stream>>>(outimg, HID_,
                                                Wlimgb + (size_t)i * KATT_ * HID_, HID_,
                                                nullptr, nullptr, timg, nullptr, KATT_);
    attn_score<<<MIMG_, 256, 0, stream>>>(timg, tu, wl_p + i * KATT_, scb);
    softmax_pool<<<B_, 256, 0, stream>>>(scb, outimg, u);
  }
}